// Round 8
// baseline (146.571 us; speedup 1.0000x reference)
//
#include <hip/hip_runtime.h>
#include <hip/hip_bf16.h>

#define NN    4096
#define BB    4
#define CIN_  128
#define CKEY_ 64
#define COUT_ 128

typedef __attribute__((ext_vector_type(8))) short bf16x8;
typedef __attribute__((ext_vector_type(4))) short bf16x4;
typedef __attribute__((ext_vector_type(4))) float f32x4;

#define MFMA16 __builtin_amdgcn_mfma_f32_16x16x32_bf16
// swizzled LDS offset (shorts) for [row][chunk c of 8 shorts], 64-short rows
#define SWK(row, c) ((((row) << 6)) + ((((c) ^ ((row) & 7))) << 3))

__device__ __forceinline__ float bf2f(short s) {
    union { unsigned int u; float f; } c; c.u = ((unsigned int)(unsigned short)s) << 16; return c.f;
}
__device__ __forceinline__ short f2bf(float f) {
    union { float f; unsigned int u; } c; c.f = f;
    unsigned int r = c.u + 0x7fffu + ((c.u >> 16) & 1u);  // RNE
    return (short)(r >> 16);
}
__device__ __forceinline__ float fexp2(float x) {
#if __has_builtin(__builtin_amdgcn_exp2f)
    return __builtin_amdgcn_exp2f(x);
#else
    return exp2f(x);
#endif
}
// word = bf16(a) | bf16(b)<<16 (round-half-up)
__device__ __forceinline__ unsigned int pack_bf16(float a, float b) {
    union { float f; unsigned int u; } ca, cb; ca.f = a; cb.f = b;
    unsigned int ua = ca.u + 0x8000u, ub = cb.u + 0x8000u;
#if __has_builtin(__builtin_amdgcn_perm)
    return __builtin_amdgcn_perm(ub, ua, 0x07060302u);
#else
    return (ua >> 16) | (ub & 0xffff0000u);
#endif
}

// ---------------- Kernel 0: W -> A-fragment layout, bf16 hi/lo ----------------
// Whf/Wlf[g 0..15][kc 0..3][quad 0..3][m 0..15][8]; out = g*16+m (0..63 Q*log2e,
// 64..127 K, 128..255 V); k = kc*32 + quad*8 + j.
__global__ __launch_bounds__(256) void wcvt_kernel(const float* __restrict__ Wq,
                                                   const float* __restrict__ Wk,
                                                   const float* __restrict__ Wv,
                                                   short* __restrict__ Whf,
                                                   short* __restrict__ Wlf) {
    int id   = blockIdx.x * 256 + threadIdx.x;   // 4096 frag-slots
    int l15  = id & 15;
    int quad = (id >> 4) & 3;
    int kc   = (id >> 6) & 3;
    int g    = id >> 8;
    int out  = g * 16 + l15;
    int k0   = kc * 32 + quad * 8;

    const float* src;
    float scale = 1.0f;
    if (out < 64)       { src = Wq + out * CIN_;         scale = 1.4426950408889634f; }
    else if (out < 128) { src = Wk + (out - 64) * CIN_; }
    else                { src = Wv + (out - 128) * CIN_; }

    bf16x8 h8, l8;
#pragma unroll
    for (int j = 0; j < 8; ++j) {
        float w = src[k0 + j] * scale;
        short h = f2bf(w);
        h8[j] = h;
        l8[j] = f2bf(w - bf2f(h));
    }
    *(bf16x8*)(Whf + id * 8) = h8;
    *(bf16x8*)(Wlf + id * 8) = l8;
}

// ---------------- Kernel 1: projections via MFMA ----------------
// grid (N/64, B, 2). z=0: rowgroups 0..7 (Q,K); z=1: 8..15 (V). Wave w sweeps
// rowgroups {gz*8 + w, gz*8 + 4 + w}. No min-waves bound: allocator uncapped
// (r5 lesson — capping below working set spills to scratch).
__global__ __launch_bounds__(256) void proj_kernel(const float* __restrict__ x,
                                                   const short* __restrict__ Whf,
                                                   const short* __restrict__ Wlf,
                                                   short* __restrict__ Qh, short* __restrict__ Ql,
                                                   short* __restrict__ Kh, short* __restrict__ Kl,
                                                   short* __restrict__ Vb) {
    __shared__ __align__(16) short xsh[16 * 64 * 8];
    __shared__ __align__(16) short xsl[16 * 64 * 8];

    int tid  = threadIdx.x;
    int b    = blockIdx.y;
    int gz   = blockIdx.z;
    int gn0  = blockIdx.x * 64;
    int wave = tid >> 6;
    int lane = tid & 63;
    int quad = lane >> 4;
    int l15  = lane & 15;

    // stage x -> bf16 hi/lo B-frag layout
    const float* xb = x + (size_t)b * CIN_ * NN + gn0;
#pragma unroll
    for (int rep = 0; rep < 4; ++rep) {
        int slot = rep * 256 + tid;
        int c = slot >> 6, n = slot & 63;
        bf16x8 h8, l8;
#pragma unroll
        for (int j = 0; j < 8; ++j) {
            float f = xb[(c * 8 + j) * NN + n];
            short h = f2bf(f);
            h8[j] = h;
            l8[j] = f2bf(f - bf2f(h));
        }
        *(bf16x8*)(xsh + (c * 64 + n) * 8) = h8;
        *(bf16x8*)(xsl + (c * 64 + n) * 8) = l8;
    }
    __syncthreads();

#pragma unroll
    for (int rr = 0; rr < 2; ++rr) {
        int rg = gz * 8 + rr * 4 + wave;
        f32x4 acc[4];
#pragma unroll
        for (int ct = 0; ct < 4; ++ct) acc[ct] = (f32x4){0.f, 0.f, 0.f, 0.f};

#pragma unroll
        for (int kc = 0; kc < 4; ++kc) {
            bf16x8 wh = *(const bf16x8*)(Whf + ((((rg * 4 + kc) * 4 + quad) * 16) + l15) * 8);
            bf16x8 wl = *(const bf16x8*)(Wlf + ((((rg * 4 + kc) * 4 + quad) * 16) + l15) * 8);
#pragma unroll
            for (int ct = 0; ct < 4; ++ct) {
                bf16x8 xh = *(const bf16x8*)(xsh + (((kc * 4 + quad) * 64) + ct * 16 + l15) * 8);
                bf16x8 xl = *(const bf16x8*)(xsl + (((kc * 4 + quad) * 64) + ct * 16 + l15) * 8);
                acc[ct] = MFMA16(wh, xh, acc[ct], 0, 0, 0);
                acc[ct] = MFMA16(wh, xl, acc[ct], 0, 0, 0);
                acc[ct] = MFMA16(wl, xh, acc[ct], 0, 0, 0);
            }
        }

        if (rg < 8) {
            short* H = (rg < 4) ? Qh : Kh;
            short* L = (rg < 4) ? Ql : Kl;
            int rb    = (rg < 4) ? rg : (rg - 4);
            int chunk = rb * 2 + (quad >> 1);
            int sub   = (quad & 1) * 4;
#pragma unroll
            for (int ct = 0; ct < 4; ++ct) {
                int n = gn0 + ct * 16 + l15;
                bf16x4 h4, l4;
#pragma unroll
                for (int r = 0; r < 4; ++r) {
                    float f = acc[ct][r];
                    short h = f2bf(f);
                    h4[r] = h;
                    l4[r] = f2bf(f - bf2f(h));
                }
                *(bf16x4*)(H + (((b * 8 + chunk) * NN) + n) * 8 + sub) = h4;
                *(bf16x4*)(L + (((b * 8 + chunk) * NN) + n) * 8 + sub) = l4;
            }
        } else {
            int o0 = rg * 16 + quad * 4 - 128;
#pragma unroll
            for (int ct = 0; ct < 4; ++ct) {
                int n = gn0 + ct * 16 + l15;
#pragma unroll
                for (int r = 0; r < 4; ++r)
                    Vb[((size_t)(b * COUT_ + o0 + r)) * NN + n] = f2bf(acc[ct][r]);
            }
        }
    }
}

// ---------------- Kernel 2: flash attention (S^T, 32 queries/wave) ----------------
// grid (B*S, N/128), block 256 (4 waves x 32 queries). Each K/V LDS fragment is
// read ONCE and feeds both 16-query sets. S=8 -> 1024 blocks = 4/CU (VGPR=128
// allows 4 waves/SIMD; r7's S=4 grid of 512 was the occupancy binder).
// (256,2): working set fits in 128 VGPR naturally; don't cap tighter (r5).
__global__ __launch_bounds__(256, 2) void flash_kernel(const short* __restrict__ Qh,
                                                       const short* __restrict__ Ql,
                                                       const short* __restrict__ Kh,
                                                       const short* __restrict__ Kl,
                                                       const short* __restrict__ Vb,
                                                       float* __restrict__ outp,
                                                       float* __restrict__ ml,
                                                       int S, int direct) {
    __shared__ __align__(16) short KhT[64 * 64];   // 8 KB, swizzled
    __shared__ __align__(16) short KlT[64 * 64];   // 8 KB
    __shared__ __align__(16) short VT[128 * 64];   // 16 KB

    int tid  = threadIdx.x;
    int bx   = blockIdx.x;
    int b    = bx / S;
    int s    = bx - b * S;
    int qt   = blockIdx.y;
    int wave = tid >> 6;
    int lane = tid & 63;
    int quad = lane >> 4;
    int l15  = lane & 15;

    // Q B-operand frags for two query sets (u=0,1), dim chunks quad and 4+quad
    int nq0 = qt * 128 + wave * 32 + l15;
    bf16x8 qh0[2], qh1[2], ql0[2], ql1[2];
#pragma unroll
    for (int u = 0; u < 2; ++u) {
        int nq = nq0 + u * 16;
        qh0[u] = *(const bf16x8*)(Qh + (((b * 8 + quad)     * NN) + nq) * 8);
        qh1[u] = *(const bf16x8*)(Qh + (((b * 8 + 4 + quad) * NN) + nq) * 8);
        ql0[u] = *(const bf16x8*)(Ql + (((b * 8 + quad)     * NN) + nq) * 8);
        ql1[u] = *(const bf16x8*)(Ql + (((b * 8 + 4 + quad) * NN) + nq) * 8);
    }

    f32x4 O[2][8];
#pragma unroll
    for (int u = 0; u < 2; ++u)
#pragma unroll
        for (int f = 0; f < 8; ++f) O[u][f] = (f32x4){0.f, 0.f, 0.f, 0.f};
    float m_i[2] = {-1.0e30f, -1.0e30f}, l_i[2] = {0.f, 0.f};

    int krow = tid & 63, kc2 = (tid >> 6) * 2;      // K: rows x chunks {kc2,kc2+1}
    int vrow = tid & 127, vc0 = (tid >> 7) * 4;     // V: rows x chunks {vc0..vc0+3}
    int sl0 = (quad & 1) * 32 + l15;                // P-permute source lanes
    int sl1 = sl0 + 16;
    int fsel = quad >> 1;

    int KPS   = NN / S;
    int kb    = s * KPS;
    int iters = KPS / 64;

    const short* KhB = Kh + (size_t)b * 8 * NN * 8;
    const short* KlB = Kl + (size_t)b * 8 * NN * 8;
    const short* VbB = Vb + (size_t)b * COUT_ * NN;

    // initial prefetch into regs
    bf16x8 nkh[2], nkl[2], nv[4];
#pragma unroll
    for (int cc = 0; cc < 2; ++cc) {
        int c = kc2 + cc;
        nkh[cc] = *(const bf16x8*)(KhB + ((c * NN) + kb + krow) * 8);
        nkl[cc] = *(const bf16x8*)(KlB + ((c * NN) + kb + krow) * 8);
    }
#pragma unroll
    for (int q = 0; q < 4; ++q)
        nv[q] = *(const bf16x8*)(VbB + (size_t)vrow * NN + kb + (vc0 + q) * 8);

    for (int it = 0; it < iters; ++it) {
        // ---- commit prefetched tile to LDS (swizzled) ----
#pragma unroll
        for (int cc = 0; cc < 2; ++cc) {
            int c = kc2 + cc;
            *(bf16x8*)(KhT + SWK(krow, c)) = nkh[cc];
            *(bf16x8*)(KlT + SWK(krow, c)) = nkl[cc];
        }
#pragma unroll
        for (int q = 0; q < 4; ++q)
            *(bf16x8*)(VT + SWK(vrow, vc0 + q)) = nv[q];
        __syncthreads();

        // ---- prefetch next tile (overlaps compute) ----
        if (it + 1 < iters) {
            int nb = kb + 64;
#pragma unroll
            for (int cc = 0; cc < 2; ++cc) {
                int c = kc2 + cc;
                nkh[cc] = *(const bf16x8*)(KhB + ((c * NN) + nb + krow) * 8);
                nkl[cc] = *(const bf16x8*)(KlB + ((c * NN) + nb + krow) * 8);
            }
#pragma unroll
            for (int q = 0; q < 4; ++q)
                nv[q] = *(const bf16x8*)(VbB + (size_t)vrow * NN + nb + (vc0 + q) * 8);
        }

        // ---- S^T = Kh·Qh + Kl·Qh + Kh·Ql, both query sets per K-frag load ----
        f32x4 sA[2][4];
#pragma unroll
        for (int f = 0; f < 4; ++f) {
            int row = f * 16 + l15;
            bf16x8 kh0 = *(const bf16x8*)(KhT + SWK(row, quad));
            bf16x8 kh1 = *(const bf16x8*)(KhT + SWK(row, 4 + quad));
            bf16x8 kl0 = *(const bf16x8*)(KlT + SWK(row, quad));
            bf16x8 kl1 = *(const bf16x8*)(KlT + SWK(row, 4 + quad));
#pragma unroll
            for (int u = 0; u < 2; ++u) {
                f32x4 acc = (f32x4){0.f, 0.f, 0.f, 0.f};
                acc = MFMA16(kh0, qh0[u], acc, 0, 0, 0);
                acc = MFMA16(kh1, qh1[u], acc, 0, 0, 0);
                acc = MFMA16(kl0, qh0[u], acc, 0, 0, 0);
                acc = MFMA16(kl1, qh1[u], acc, 0, 0, 0);
                acc = MFMA16(kh0, ql0[u], acc, 0, 0, 0);
                acc = MFMA16(kh1, ql1[u], acc, 0, 0, 0);
                sA[u][f] = acc;
            }
        }

        // ---- online softmax + P pack/permute + PV, per set ----
        unsigned int pw[2][4][2];
#pragma unroll
        for (int u = 0; u < 2; ++u) {
            float vm = sA[u][0][0];
#pragma unroll
            for (int f = 0; f < 4; ++f)
#pragma unroll
                for (int r = 0; r < 4; ++r) vm = fmaxf(vm, sA[u][f][r]);
            vm = fmaxf(vm, __shfl_xor(vm, 16, 64));
            vm = fmaxf(vm, __shfl_xor(vm, 32, 64));
            float nm    = fmaxf(m_i[u], vm);
            float alpha = fexp2(m_i[u] - nm);
            m_i[u] = nm;

            float p[4][4];
            float rs = 0.f;
#pragma unroll
            for (int f = 0; f < 4; ++f)
#pragma unroll
                for (int r = 0; r < 4; ++r) {
                    float pv = fexp2(sA[u][f][r] - nm);
                    p[f][r] = pv;
                    rs += pv;
                }
            rs += __shfl_xor(rs, 16, 64);
            rs += __shfl_xor(rs, 32, 64);
            l_i[u] = l_i[u] * alpha + rs;

            if (__any(alpha < 1.0f)) {
#pragma unroll
                for (int f = 0; f < 8; ++f)
#pragma unroll
                    for (int r = 0; r < 4; ++r) O[u][f][r] *= alpha;
            }
#pragma unroll
            for (int f = 0; f < 4; ++f) {
                pw[u][f][0] = pack_bf16(p[f][0], p[f][1]);
                pw[u][f][1] = pack_bf16(p[f][2], p[f][3]);
            }
        }

#pragma unroll
        for (int g = 0; g < 2; ++g) {
            union { int i[4]; bf16x8 v; } pb[2];
#pragma unroll
            for (int u = 0; u < 2; ++u) {
                int a0 = __shfl((int)pw[u][g * 2][0],     sl0, 64);
                int a1 = __shfl((int)pw[u][g * 2][1],     sl0, 64);
                int a2 = __shfl((int)pw[u][g * 2][0],     sl1, 64);
                int a3 = __shfl((int)pw[u][g * 2][1],     sl1, 64);
                int b0 = __shfl((int)pw[u][g * 2 + 1][0], sl0, 64);
                int b1 = __shfl((int)pw[u][g * 2 + 1][1], sl0, 64);
                int b2 = __shfl((int)pw[u][g * 2 + 1][0], sl1, 64);
                int b3 = __shfl((int)pw[u][g * 2 + 1][1], sl1, 64);
                pb[u].i[0] = fsel ? b0 : a0;
                pb[u].i[1] = fsel ? b1 : a1;
                pb[u].i[2] = fsel ? b2 : a2;
                pb[u].i[3] = fsel ? b3 : a3;
            }
#pragma unroll
            for (int f8 = 0; f8 < 8; ++f8) {
                bf16x8 vA = *(const bf16x8*)(VT + SWK(f8 * 16 + l15, g * 4 + quad));
                O[0][f8] = MFMA16(vA, pb[0].v, O[0][f8], 0, 0, 0);
                O[1][f8] = MFMA16(vA, pb[1].v, O[1][f8], 0, 0, 0);
            }
        }
        __syncthreads();
        kb += 64;
    }

    // ---- epilogue ----
#pragma unroll
    for (int u = 0; u < 2; ++u) {
        int n = nq0 + u * 16;
        if (direct) {
            float inv = 1.f / l_i[u];
#pragma unroll
            for (int f8 = 0; f8 < 8; ++f8)
#pragma unroll
                for (int r = 0; r < 4; ++r) {
                    int o = f8 * 16 + quad * 4 + r;
                    outp[((size_t)(b * COUT_ + o)) * NN + n] = O[u][f8][r] * inv;
                }
        } else {
#pragma unroll
            for (int f8 = 0; f8 < 8; ++f8)
#pragma unroll
                for (int r = 0; r < 4; ++r) {
                    int o = f8 * 16 + quad * 4 + r;
                    outp[((size_t)((b * S + s) * COUT_ + o)) * NN + n] = O[u][f8][r];
                }
            if (quad == 0) {
                ml[((b * S + s) * 2 + 0) * NN + n] = m_i[u];
                ml[((b * S + s) * 2 + 1) * NN + n] = l_i[u];
            }
        }
    }
}

// ---------------- Kernel 3: merge K-split partials ----------------
__global__ __launch_bounds__(256, 4) void merge_kernel(const float* __restrict__ Opart,
                                                       const float* __restrict__ ml,
                                                       float* __restrict__ out, int S) {
    int idx = blockIdx.x * 256 + threadIdx.x;   // over B*COUT*N/4
    int n0  = (idx & (NN / 4 - 1)) * 4;
    int rest = idx >> 10;
    int o = rest & (COUT_ - 1);
    int b = rest >> 7;

    f32x4 gm = (f32x4){-1.0e30f, -1.0e30f, -1.0e30f, -1.0e30f};
    for (int s = 0; s < S; ++s) {
        f32x4 m = *(const f32x4*)(ml + ((b * S + s) * 2 + 0) * NN + n0);
#pragma unroll
        for (int j = 0; j < 4; ++j) gm[j] = fmaxf(gm[j], m[j]);
    }
    f32x4 acc = (f32x4){0.f, 0.f, 0.f, 0.f};
    f32x4 den = (f32x4){0.f, 0.f, 0.f, 0.f};
    for (int s = 0; s < S; ++s) {
        f32x4 m = *(const f32x4*)(ml + ((b * S + s) * 2 + 0) * NN + n0);
        f32x4 l = *(const f32x4*)(ml + ((b * S + s) * 2 + 1) * NN + n0);
        f32x4 ov = *(const f32x4*)(Opart + ((size_t)((b * S + s) * COUT_ + o)) * NN + n0);
#pragma unroll
        for (int j = 0; j < 4; ++j) {
            float ws = fexp2(m[j] - gm[j]);
            acc[j] = fmaf(ws, ov[j], acc[j]);
            den[j] = fmaf(ws, l[j], den[j]);
        }
    }
    f32x4 res;
#pragma unroll
    for (int j = 0; j < 4; ++j) res[j] = acc[j] / den[j];
    *(f32x4*)(out + ((size_t)(b * COUT_ + o)) * NN + n0) = res;
}

extern "C" void kernel_launch(void* const* d_in, const int* in_sizes, int n_in,
                              void* d_out, int out_size, void* d_ws, size_t ws_size,
                              hipStream_t stream) {
    const float* x  = (const float*)d_in[0];
    const float* Wq = (const float*)d_in[1];
    const float* Wk = (const float*)d_in[2];
    const float* Wv = (const float*)d_in[3];

    char* ws = (char*)d_ws;
    short* Whf = (short*)ws;                         // 65536 B
    short* Wlf = (short*)(ws + 65536);               // 65536 B
    short* Qh = (short*)(ws + 131072);               // 4 x 2 MB
    short* Ql = Qh + 1048576;
    short* Kh = Ql + 1048576;
    short* Kl = Kh + 1048576;
    short* Vb = Kl + 1048576;                        // 4 MB
    size_t base = 131072 + 4ull * 2097152 + 4194304; // 12.7 MB
    const size_t OPART = 8388608;                    // B*COUT*N*4 per split
    const size_t MLSZ  = 131072;                     // B*2*N*4 per split

    int S;
    if      (ws_size >= base + 8 * (OPART + MLSZ)) S = 8;
    else if (ws_size >= base + 4 * (OPART + MLSZ)) S = 4;
    else if (ws_size >= base + 2 * (OPART + MLSZ)) S = 2;
    else                                           S = 1;
    int direct = (S == 1);

    float* mlp   = (float*)(ws + base);
    float* Opart = (float*)(ws + base + (size_t)S * MLSZ);

    wcvt_kernel<<<16, 256, 0, stream>>>(Wq, Wk, Wv, Whf, Wlf);
    proj_kernel<<<dim3(NN / 64, BB, 2), 256, 0, stream>>>(x, Whf, Wlf, Qh, Ql, Kh, Kl, Vb);
    flash_kernel<<<dim3(BB * S, NN / 128), 256, 0, stream>>>(
        Qh, Ql, Kh, Kl, Vb, direct ? (float*)d_out : Opart, mlp, S, direct);
    if (!direct)
        merge_kernel<<<BB * COUT_ * NN / 4 / 256, 256, 0, stream>>>(Opart, mlp, (float*)d_out, S);
}

// Round 9
// 136.458 us; speedup vs baseline: 1.0741x; 1.0741x over previous
//
#include <hip/hip_runtime.h>
#include <hip/hip_bf16.h>

#define NN    4096
#define BB    4
#define CIN_  128
#define CKEY_ 64
#define COUT_ 128

typedef __attribute__((ext_vector_type(8))) short bf16x8;
typedef __attribute__((ext_vector_type(4))) short bf16x4;
typedef __attribute__((ext_vector_type(4))) float f32x4;

#define MFMA16 __builtin_amdgcn_mfma_f32_16x16x32_bf16
// swizzled LDS offset (shorts) for [row][chunk c of 8 shorts], 64-short rows
#define SWK(row, c) ((((row) << 6)) + ((((c) ^ ((row) & 7))) << 3))

__device__ __forceinline__ float bf2f(short s) {
    union { unsigned int u; float f; } c; c.u = ((unsigned int)(unsigned short)s) << 16; return c.f;
}
__device__ __forceinline__ short f2bf(float f) {
    union { float f; unsigned int u; } c; c.f = f;
    unsigned int r = c.u + 0x7fffu + ((c.u >> 16) & 1u);  // RNE
    return (short)(r >> 16);
}
__device__ __forceinline__ float fexp2(float x) {
#if __has_builtin(__builtin_amdgcn_exp2f)
    return __builtin_amdgcn_exp2f(x);
#else
    return exp2f(x);
#endif
}
// word = bf16(a) | bf16(b)<<16 (round-half-up)
__device__ __forceinline__ unsigned int pack_bf16(float a, float b) {
    union { float f; unsigned int u; } ca, cb; ca.f = a; cb.f = b;
    unsigned int ua = ca.u + 0x8000u, ub = cb.u + 0x8000u;
#if __has_builtin(__builtin_amdgcn_perm)
    return __builtin_amdgcn_perm(ub, ua, 0x07060302u);
#else
    return (ua >> 16) | (ub & 0xffff0000u);
#endif
}

// ---------------- Kernel 0: W -> A-fragment layout, bf16 hi/lo ----------------
__global__ __launch_bounds__(256) void wcvt_kernel(const float* __restrict__ Wq,
                                                   const float* __restrict__ Wk,
                                                   const float* __restrict__ Wv,
                                                   short* __restrict__ Whf,
                                                   short* __restrict__ Wlf) {
    int id   = blockIdx.x * 256 + threadIdx.x;   // 4096 frag-slots
    int l15  = id & 15;
    int quad = (id >> 4) & 3;
    int kc   = (id >> 6) & 3;
    int g    = id >> 8;
    int out  = g * 16 + l15;
    int k0   = kc * 32 + quad * 8;

    const float* src;
    float scale = 1.0f;
    if (out < 64)       { src = Wq + out * CIN_;         scale = 1.4426950408889634f; }
    else if (out < 128) { src = Wk + (out - 64) * CIN_; }
    else                { src = Wv + (out - 128) * CIN_; }

    bf16x8 h8, l8;
#pragma unroll
    for (int j = 0; j < 8; ++j) {
        float w = src[k0 + j] * scale;
        short h = f2bf(w);
        h8[j] = h;
        l8[j] = f2bf(w - bf2f(h));
    }
    *(bf16x8*)(Whf + id * 8) = h8;
    *(bf16x8*)(Wlf + id * 8) = l8;
}

// ---------------- Kernel 1: projections via MFMA ----------------
// grid (N/64, B, 2). z=0: rowgroups 0..7 (Q,K); z=1: 8..15 (V).
__global__ __launch_bounds__(256) void proj_kernel(const float* __restrict__ x,
                                                   const short* __restrict__ Whf,
                                                   const short* __restrict__ Wlf,
                                                   short* __restrict__ Qh, short* __restrict__ Ql,
                                                   short* __restrict__ Kh, short* __restrict__ Kl,
                                                   short* __restrict__ Vb) {
    __shared__ __align__(16) short xsh[16 * 64 * 8];
    __shared__ __align__(16) short xsl[16 * 64 * 8];

    int tid  = threadIdx.x;
    int b    = blockIdx.y;
    int gz   = blockIdx.z;
    int gn0  = blockIdx.x * 64;
    int wave = tid >> 6;
    int lane = tid & 63;
    int quad = lane >> 4;
    int l15  = lane & 15;

    const float* xb = x + (size_t)b * CIN_ * NN + gn0;
#pragma unroll
    for (int rep = 0; rep < 4; ++rep) {
        int slot = rep * 256 + tid;
        int c = slot >> 6, n = slot & 63;
        bf16x8 h8, l8;
#pragma unroll
        for (int j = 0; j < 8; ++j) {
            float f = xb[(c * 8 + j) * NN + n];
            short h = f2bf(f);
            h8[j] = h;
            l8[j] = f2bf(f - bf2f(h));
        }
        *(bf16x8*)(xsh + (c * 64 + n) * 8) = h8;
        *(bf16x8*)(xsl + (c * 64 + n) * 8) = l8;
    }
    __syncthreads();

#pragma unroll
    for (int rr = 0; rr < 2; ++rr) {
        int rg = gz * 8 + rr * 4 + wave;
        f32x4 acc[4];
#pragma unroll
        for (int ct = 0; ct < 4; ++ct) acc[ct] = (f32x4){0.f, 0.f, 0.f, 0.f};

#pragma unroll
        for (int kc = 0; kc < 4; ++kc) {
            bf16x8 wh = *(const bf16x8*)(Whf + ((((rg * 4 + kc) * 4 + quad) * 16) + l15) * 8);
            bf16x8 wl = *(const bf16x8*)(Wlf + ((((rg * 4 + kc) * 4 + quad) * 16) + l15) * 8);
#pragma unroll
            for (int ct = 0; ct < 4; ++ct) {
                bf16x8 xh = *(const bf16x8*)(xsh + (((kc * 4 + quad) * 64) + ct * 16 + l15) * 8);
                bf16x8 xl = *(const bf16x8*)(xsl + (((kc * 4 + quad) * 64) + ct * 16 + l15) * 8);
                acc[ct] = MFMA16(wh, xh, acc[ct], 0, 0, 0);
                acc[ct] = MFMA16(wh, xl, acc[ct], 0, 0, 0);
                acc[ct] = MFMA16(wl, xh, acc[ct], 0, 0, 0);
            }
        }

        if (rg < 8) {
            short* H = (rg < 4) ? Qh : Kh;
            short* L = (rg < 4) ? Ql : Kl;
            int rb    = (rg < 4) ? rg : (rg - 4);
            int chunk = rb * 2 + (quad >> 1);
            int sub   = (quad & 1) * 4;
#pragma unroll
            for (int ct = 0; ct < 4; ++ct) {
                int n = gn0 + ct * 16 + l15;
                bf16x4 h4, l4;
#pragma unroll
                for (int r = 0; r < 4; ++r) {
                    float f = acc[ct][r];
                    short h = f2bf(f);
                    h4[r] = h;
                    l4[r] = f2bf(f - bf2f(h));
                }
                *(bf16x4*)(H + (((b * 8 + chunk) * NN) + n) * 8 + sub) = h4;
                *(bf16x4*)(L + (((b * 8 + chunk) * NN) + n) * 8 + sub) = l4;
            }
        } else {
            int o0 = rg * 16 + quad * 4 - 128;
#pragma unroll
            for (int ct = 0; ct < 4; ++ct) {
                int n = gn0 + ct * 16 + l15;
#pragma unroll
                for (int r = 0; r < 4; ++r)
                    Vb[((size_t)(b * COUT_ + o0 + r)) * NN + n] = f2bf(acc[ct][r]);
            }
        }
    }
}

// ---------------- Kernel 2: flash attention (S^T, 32 q/wave, K direct-from-global) ----------------
// K fragments are loaded straight global->reg each iteration (coalesced; L2-served;
// skips LDS entirely -- r8 post-mortem: LDS pipe was the tallest pole and K was half
// of it). V stays LDS-staged (its fragment gather is stride-NN uncoalesced).
// S=4 (r8: S=8 diluted per-block work and thrashed L2 -- regressed).
__global__ __launch_bounds__(256, 2) void flash_kernel(const short* __restrict__ Qh,
                                                       const short* __restrict__ Ql,
                                                       const short* __restrict__ Kh,
                                                       const short* __restrict__ Kl,
                                                       const short* __restrict__ Vb,
                                                       float* __restrict__ outp,
                                                       float* __restrict__ ml,
                                                       int S, int direct) {
    __shared__ __align__(16) short VT[128 * 64];   // 16 KB, swizzled

    int tid  = threadIdx.x;
    int bx   = blockIdx.x;
    int b    = bx / S;
    int s    = bx - b * S;
    int qt   = blockIdx.y;
    int wave = tid >> 6;
    int lane = tid & 63;
    int quad = lane >> 4;
    int l15  = lane & 15;

    // Q B-operand frags for two query sets (u=0,1), dim chunks quad and 4+quad
    int nq0 = qt * 128 + wave * 32 + l15;
    bf16x8 qh0[2], qh1[2], ql0[2], ql1[2];
#pragma unroll
    for (int u = 0; u < 2; ++u) {
        int nq = nq0 + u * 16;
        qh0[u] = *(const bf16x8*)(Qh + (((b * 8 + quad)     * NN) + nq) * 8);
        qh1[u] = *(const bf16x8*)(Qh + (((b * 8 + 4 + quad) * NN) + nq) * 8);
        ql0[u] = *(const bf16x8*)(Ql + (((b * 8 + quad)     * NN) + nq) * 8);
        ql1[u] = *(const bf16x8*)(Ql + (((b * 8 + 4 + quad) * NN) + nq) * 8);
    }

    f32x4 O[2][8];
#pragma unroll
    for (int u = 0; u < 2; ++u)
#pragma unroll
        for (int f = 0; f < 8; ++f) O[u][f] = (f32x4){0.f, 0.f, 0.f, 0.f};
    float m_i[2] = {-1.0e30f, -1.0e30f}, l_i[2] = {0.f, 0.f};

    int vrow = tid & 127, vc0 = (tid >> 7) * 4;     // V: rows x chunks {vc0..vc0+3}
    int sl0 = (quad & 1) * 32 + l15;                // P-permute source lanes
    int sl1 = sl0 + 16;
    int fsel = quad >> 1;

    int KPS   = NN / S;
    int kb    = s * KPS;
    int iters = KPS / 64;

    const short* KhB = Kh + (size_t)b * 8 * NN * 8;
    const short* KlB = Kl + (size_t)b * 8 * NN * 8;
    const short* VbB = Vb + (size_t)b * COUT_ * NN;

    // initial V prefetch into regs
    bf16x8 nv[4];
#pragma unroll
    for (int q = 0; q < 4; ++q)
        nv[q] = *(const bf16x8*)(VbB + (size_t)vrow * NN + kb + (vc0 + q) * 8);

    for (int it = 0; it < iters; ++it) {
        // ---- K fragment loads for THIS iter, straight from global (no LDS dep) ----
        bf16x8 kh0[4], kh1[4], kl0[4], kl1[4];
#pragma unroll
        for (int f = 0; f < 4; ++f) {
            int row = kb + f * 16 + l15;
            kh0[f] = *(const bf16x8*)(KhB + ((quad       * NN) + row) * 8);
            kh1[f] = *(const bf16x8*)(KhB + (((4 + quad) * NN) + row) * 8);
            kl0[f] = *(const bf16x8*)(KlB + ((quad       * NN) + row) * 8);
            kl1[f] = *(const bf16x8*)(KlB + (((4 + quad) * NN) + row) * 8);
        }

        // ---- commit prefetched V tile to LDS (swizzled) ----
#pragma unroll
        for (int q = 0; q < 4; ++q)
            *(bf16x8*)(VT + SWK(vrow, vc0 + q)) = nv[q];
        __syncthreads();

        // ---- prefetch next V tile ----
        if (it + 1 < iters) {
            int nb = kb + 64;
#pragma unroll
            for (int q = 0; q < 4; ++q)
                nv[q] = *(const bf16x8*)(VbB + (size_t)vrow * NN + nb + (vc0 + q) * 8);
        }

        // ---- S^T = Kh·Qh + Kl·Qh + Kh·Ql, both query sets per K-frag ----
        f32x4 sA[2][4];
#pragma unroll
        for (int f = 0; f < 4; ++f) {
#pragma unroll
            for (int u = 0; u < 2; ++u) {
                f32x4 acc = (f32x4){0.f, 0.f, 0.f, 0.f};
                acc = MFMA16(kh0[f], qh0[u], acc, 0, 0, 0);
                acc = MFMA16(kh1[f], qh1[u], acc, 0, 0, 0);
                acc = MFMA16(kl0[f], qh0[u], acc, 0, 0, 0);
                acc = MFMA16(kl1[f], qh1[u], acc, 0, 0, 0);
                acc = MFMA16(kh0[f], ql0[u], acc, 0, 0, 0);
                acc = MFMA16(kh1[f], ql1[u], acc, 0, 0, 0);
                sA[u][f] = acc;
            }
        }

        // ---- online softmax + P pack, per set ----
        unsigned int pw[2][4][2];
#pragma unroll
        for (int u = 0; u < 2; ++u) {
            float vm = sA[u][0][0];
#pragma unroll
            for (int f = 0; f < 4; ++f)
#pragma unroll
                for (int r = 0; r < 4; ++r) vm = fmaxf(vm, sA[u][f][r]);
            vm = fmaxf(vm, __shfl_xor(vm, 16, 64));
            vm = fmaxf(vm, __shfl_xor(vm, 32, 64));
            float nm    = fmaxf(m_i[u], vm);
            float alpha = fexp2(m_i[u] - nm);
            m_i[u] = nm;

            float p[4][4];
            float rs = 0.f;
#pragma unroll
            for (int f = 0; f < 4; ++f)
#pragma unroll
                for (int r = 0; r < 4; ++r) {
                    float pv = fexp2(sA[u][f][r] - nm);
                    p[f][r] = pv;
                    rs += pv;
                }
            rs += __shfl_xor(rs, 16, 64);
            rs += __shfl_xor(rs, 32, 64);
            l_i[u] = l_i[u] * alpha + rs;

            if (__any(alpha < 1.0f)) {
#pragma unroll
                for (int f = 0; f < 8; ++f)
#pragma unroll
                    for (int r = 0; r < 4; ++r) O[u][f][r] *= alpha;
            }
#pragma unroll
            for (int f = 0; f < 4; ++f) {
                pw[u][f][0] = pack_bf16(p[f][0], p[f][1]);
                pw[u][f][1] = pack_bf16(p[f][2], p[f][3]);
            }
        }

        // ---- P permute (post-shuffle select) + PV MFMAs from VT ----
#pragma unroll
        for (int g = 0; g < 2; ++g) {
            union { int i[4]; bf16x8 v; } pb[2];
#pragma unroll
            for (int u = 0; u < 2; ++u) {
                int a0 = __shfl((int)pw[u][g * 2][0],     sl0, 64);
                int a1 = __shfl((int)pw[u][g * 2][1],     sl0, 64);
                int a2 = __shfl((int)pw[u][g * 2][0],     sl1, 64);
                int a3 = __shfl((int)pw[u][g * 2][1],     sl1, 64);
                int b0 = __shfl((int)pw[u][g * 2 + 1][0], sl0, 64);
                int b1 = __shfl((int)pw[u][g * 2 + 1][1], sl0, 64);
                int b2 = __shfl((int)pw[u][g * 2 + 1][0], sl1, 64);
                int b3 = __shfl((int)pw[u][g * 2 + 1][1], sl1, 64);
                pb[u].i[0] = fsel ? b0 : a0;
                pb[u].i[1] = fsel ? b1 : a1;
                pb[u].i[2] = fsel ? b2 : a2;
                pb[u].i[3] = fsel ? b3 : a3;
            }
#pragma unroll
            for (int f8 = 0; f8 < 8; ++f8) {
                bf16x8 vA = *(const bf16x8*)(VT + SWK(f8 * 16 + l15, g * 4 + quad));
                O[0][f8] = MFMA16(vA, pb[0].v, O[0][f8], 0, 0, 0);
                O[1][f8] = MFMA16(vA, pb[1].v, O[1][f8], 0, 0, 0);
            }
        }
        __syncthreads();
        kb += 64;
    }

    // ---- epilogue ----
#pragma unroll
    for (int u = 0; u < 2; ++u) {
        int n = nq0 + u * 16;
        if (direct) {
            float inv = 1.f / l_i[u];
#pragma unroll
            for (int f8 = 0; f8 < 8; ++f8)
#pragma unroll
                for (int r = 0; r < 4; ++r) {
                    int o = f8 * 16 + quad * 4 + r;
                    outp[((size_t)(b * COUT_ + o)) * NN + n] = O[u][f8][r] * inv;
                }
        } else {
#pragma unroll
            for (int f8 = 0; f8 < 8; ++f8)
#pragma unroll
                for (int r = 0; r < 4; ++r) {
                    int o = f8 * 16 + quad * 4 + r;
                    outp[((size_t)((b * S + s) * COUT_ + o)) * NN + n] = O[u][f8][r];
                }
            if (quad == 0) {
                ml[((b * S + s) * 2 + 0) * NN + n] = m_i[u];
                ml[((b * S + s) * 2 + 1) * NN + n] = l_i[u];
            }
        }
    }
}

// ---------------- Kernel 3: merge K-split partials ----------------
__global__ __launch_bounds__(256, 4) void merge_kernel(const float* __restrict__ Opart,
                                                       const float* __restrict__ ml,
                                                       float* __restrict__ out, int S) {
    int idx = blockIdx.x * 256 + threadIdx.x;   // over B*COUT*N/4
    int n0  = (idx & (NN / 4 - 1)) * 4;
    int rest = idx >> 10;
    int o = rest & (COUT_ - 1);
    int b = rest >> 7;

    f32x4 gm = (f32x4){-1.0e30f, -1.0e30f, -1.0e30f, -1.0e30f};
    for (int s = 0; s < S; ++s) {
        f32x4 m = *(const f32x4*)(ml + ((b * S + s) * 2 + 0) * NN + n0);
#pragma unroll
        for (int j = 0; j < 4; ++j) gm[j] = fmaxf(gm[j], m[j]);
    }
    f32x4 acc = (f32x4){0.f, 0.f, 0.f, 0.f};
    f32x4 den = (f32x4){0.f, 0.f, 0.f, 0.f};
    for (int s = 0; s < S; ++s) {
        f32x4 m = *(const f32x4*)(ml + ((b * S + s) * 2 + 0) * NN + n0);
        f32x4 l = *(const f32x4*)(ml + ((b * S + s) * 2 + 1) * NN + n0);
        f32x4 ov = *(const f32x4*)(Opart + ((size_t)((b * S + s) * COUT_ + o)) * NN + n0);
#pragma unroll
        for (int j = 0; j < 4; ++j) {
            float ws = fexp2(m[j] - gm[j]);
            acc[j] = fmaf(ws, ov[j], acc[j]);
            den[j] = fmaf(ws, l[j], den[j]);
        }
    }
    f32x4 res;
#pragma unroll
    for (int j = 0; j < 4; ++j) res[j] = acc[j] / den[j];
    *(f32x4*)(out + ((size_t)(b * COUT_ + o)) * NN + n0) = res;
}

extern "C" void kernel_launch(void* const* d_in, const int* in_sizes, int n_in,
                              void* d_out, int out_size, void* d_ws, size_t ws_size,
                              hipStream_t stream) {
    const float* x  = (const float*)d_in[0];
    const float* Wq = (const float*)d_in[1];
    const float* Wk = (const float*)d_in[2];
    const float* Wv = (const float*)d_in[3];

    char* ws = (char*)d_ws;
    short* Whf = (short*)ws;                         // 65536 B
    short* Wlf = (short*)(ws + 65536);               // 65536 B
    short* Qh = (short*)(ws + 131072);               // 4 x 2 MB
    short* Ql = Qh + 1048576;
    short* Kh = Ql + 1048576;
    short* Kl = Kh + 1048576;
    short* Vb = Kl + 1048576;                        // 4 MB
    size_t base = 131072 + 4ull * 2097152 + 4194304; // 12.7 MB
    const size_t OPART = 8388608;                    // B*COUT*N*4 per split
    const size_t MLSZ  = 131072;                     // B*2*N*4 per split

    int S;
    if      (ws_size >= base + 4 * (OPART + MLSZ)) S = 4;
    else if (ws_size >= base + 2 * (OPART + MLSZ)) S = 2;
    else                                           S = 1;
    int direct = (S == 1);

    float* mlp   = (float*)(ws + base);
    float* Opart = (float*)(ws + base + (size_t)S * MLSZ);

    wcvt_kernel<<<16, 256, 0, stream>>>(Wq, Wk, Wv, Whf, Wlf);
    proj_kernel<<<dim3(NN / 64, BB, 2), 256, 0, stream>>>(x, Whf, Wlf, Qh, Ql, Kh, Kl, Vb);
    flash_kernel<<<dim3(BB * S, NN / 128), 256, 0, stream>>>(
        Qh, Ql, Kh, Kl, Vb, direct ? (float*)d_out : Opart, mlp, S, direct);
    if (!direct)
        merge_kernel<<<BB * COUT_ * NN / 4 / 256, 256, 0, stream>>>(Opart, mlp, (float*)d_out, S);
}